// Round 1
// baseline (256.909 us; speedup 1.0000x reference)
//
#include <hip/hip_runtime.h>

// HMULayer omega: out[b][n] = exp(-(lam_n*||x_b-mu_n||^2 + sum_k om_nk*((x_b-mu_n).v_nk)^2)/D)
// B=1024, N=8192, D=256, K=8. 9 fused bf16 MFMA GEMMs sharing A=x.
// R5: persistent-B restructure.
//  - prep_w ELIMINATED: each block owns NT=16 n's; stages its [mu;v] slice
//    fp32->bf16 into LDS ONCE (72KB, whole K=256), computing mu2/muv fp32 inline.
//  - Main loop over b-tiles is BARRIER-FREE: B-frags from resident LDS
//    (9 ds_reads reused over 2 row-blocks), A-frags direct from global px
//    (512KB, L2-resident). One __syncthreads in the whole kernel.
//  - grid=512 = exactly 2 blocks/CU (153KB LDS/CU).

#define B_SZ 1024
#define N_SZ 8192
#define D_SZ 256
#define K_SZ 8

#define NT 16
#define BT 128
#define NBT (B_SZ / BT)

typedef __bf16 bf16x8 __attribute__((ext_vector_type(8)));
typedef float f32x4 __attribute__((ext_vector_type(4)));
typedef unsigned short u16x4 __attribute__((ext_vector_type(4)));
typedef unsigned short u16x8 __attribute__((ext_vector_type(8)));

// ws layout (new path): x2 f32[1024] @0 ; px bf16[1024*256] @4096
#define WS_X2 0u
#define WS_PX 4096u
#define WS_NEED_P (4096ull + 524288ull)
// old fallback offsets
#define WS_MU2F 4096u
#define WS_MUVF 36864u
#define WS_NEED_F 299008ull

__device__ __forceinline__ float wave_reduce(float s) {
#pragma unroll
  for (int off = 32; off > 0; off >>= 1) s += __shfl_down(s, off);
  return s;
}

__device__ __forceinline__ u16x4 cvt4(float4 t) {
  u16x4 r;
  r[0] = __builtin_bit_cast(unsigned short, (__bf16)t.x);
  r[1] = __builtin_bit_cast(unsigned short, (__bf16)t.y);
  r[2] = __builtin_bit_cast(unsigned short, (__bf16)t.z);
  r[3] = __builtin_bit_cast(unsigned short, (__bf16)t.w);
  return r;
}

// ---- prep_x: x2[b] + px bf16 pack. One wave per b. grid=256, block=256. ----
__global__ void prep_x(const float* __restrict__ x, float* __restrict__ x2,
                       unsigned short* __restrict__ px) {
  const int w = threadIdx.x >> 6, lane = threadIdx.x & 63;
  const int b = blockIdx.x * 4 + w;
  float4 t = *(const float4*)(x + (size_t)b * D_SZ + 4 * lane);
  *(u16x4*)(px + (size_t)b * D_SZ + 4 * lane) = cvt4(t);
  float s = t.x * t.x + t.y * t.y + t.z * t.z + t.w * t.w;
  s = wave_reduce(s);
  if (lane == 0) x2[b] = s;
}

// ---- persistent-B main: 512 blocks, one n-tile each, loops all b ----
__global__ __launch_bounds__(256, 2)
void hmu_pers(const unsigned short* __restrict__ px,
              const float* __restrict__ mu, const float* __restrict__ v,
              const float* __restrict__ lam, const float* __restrict__ om,
              const float* __restrict__ x2g, float* __restrict__ out) {
  // Bs: [kt(8)][(j*16+n)(144)][32 elems]  bf16 -> 73728 B
  __shared__ __align__(16) unsigned short Bs[8 * 144 * 32];
  __shared__ __align__(16) float x2s[B_SZ];   // 4 KB
  __shared__ float mu2s[NT];
  __shared__ float muvs[NT * K_SZ];

  const int tid = threadIdx.x;
  const int lane = tid & 63;
  const int w = tid >> 6;
  const int n0 = blockIdx.x * NT;

  // x2 -> LDS (1024 floats, one float4 per thread)
  *(float4*)(x2s + 4 * tid) = *(const float4*)(x2g + 4 * tid);

  // ---- stage B: wave w handles local n = 4w..4w+3; fp32 dots for mu2/muv ----
  const int kts = lane >> 3;        // d=4*lane -> kt slab = lane>>3
  const int c4 = (lane & 7) * 4;    // elem offset within 32-elem row
#pragma unroll 1
  for (int nn = 0; nn < 4; ++nn) {
    const int nl = w * 4 + nn;
    const int n = n0 + nl;
    float4 m4 = *(const float4*)(mu + (size_t)n * D_SZ + 4 * lane);
    *(u16x4*)&Bs[kts * 4608 + nl * 32 + c4] = cvt4(m4);
    float s2 = m4.x * m4.x + m4.y * m4.y + m4.z * m4.z + m4.w * m4.w;
    float dk[K_SZ];
#pragma unroll
    for (int k = 0; k < K_SZ; ++k) {
      float4 v4 = *(const float4*)(v + ((size_t)n * K_SZ + k) * D_SZ + 4 * lane);
      *(u16x4*)&Bs[kts * 4608 + ((k + 1) * NT + nl) * 32 + c4] = cvt4(v4);
      dk[k] = m4.x * v4.x + m4.y * v4.y + m4.z * v4.z + m4.w * v4.w;
    }
    s2 = wave_reduce(s2);
    if (lane == 0) mu2s[nl] = s2;
#pragma unroll
    for (int k = 0; k < K_SZ; ++k) {
      float r = wave_reduce(dk[k]);
      if (lane == 0) muvs[nl * K_SZ + k] = r;
    }
  }
  __syncthreads();   // the ONLY barrier

  // ---- per-lane epilogue constants (n fixed for whole kernel) ----
  const int m = lane & 15, kg = lane >> 4;
  const int n = n0 + m;
  const float lam_n = lam[n];
  const float mu2_n = mu2s[m];
  float omr[K_SZ], muvr[K_SZ];
#pragma unroll
  for (int k = 0; k < K_SZ; ++k) {
    omr[k] = om[n * K_SZ + k];
    muvr[k] = muvs[m * K_SZ + k];
  }

  // A-frag base: row (w*32 + m), col chunk kg*8
  const unsigned short* pxw = px + (size_t)(w * 32 + m) * D_SZ + kg * 8;

  for (int bt = 0; bt < NBT; ++bt) {
    const int brow = bt * BT + w * 32;
    f32x4 acc[2][9];
#pragma unroll
    for (int rb = 0; rb < 2; ++rb)
#pragma unroll
      for (int j = 0; j < 9; ++j) acc[rb][j] = (f32x4){0.f, 0.f, 0.f, 0.f};

#pragma unroll
    for (int kt = 0; kt < 8; ++kt) {
      bf16x8 bfr[9];
#pragma unroll
      for (int j = 0; j < 9; ++j)
        bfr[j] = *(const bf16x8*)&Bs[kt * 4608 + (j * NT + m) * 32 + kg * 8];
#pragma unroll
      for (int rb = 0; rb < 2; ++rb) {
        bf16x8 a = *(const bf16x8*)(pxw + ((size_t)bt * BT + rb * 16) * D_SZ + kt * 32);
#pragma unroll
        for (int j = 0; j < 9; ++j)
          acc[rb][j] = __builtin_amdgcn_mfma_f32_16x16x32_bf16(a, bfr[j], acc[rb][j], 0, 0, 0);
      }
    }

    // epilogue: C/D layout col(n)=lane&15, row(b)=kg*4+reg
#pragma unroll
    for (int rb = 0; rb < 2; ++rb)
#pragma unroll
      for (int r = 0; r < 4; ++r) {
        int b = brow + rb * 16 + kg * 4 + r;
        float x2b = x2s[b];
        float c0 = acc[rb][0][r];
        float q = lam_n * (x2b - 2.f * c0 + mu2_n);
#pragma unroll
        for (int k = 0; k < K_SZ; ++k) {
          float p = acc[rb][k + 1][r] - muvr[k];
          q = fmaf(omr[k] * p, p, q);
        }
        out[(size_t)b * N_SZ + n] = __expf(q * (-1.0f / 256.0f));
      }
  }
}

// ================= fallback path (R2): in-loop cvt staging =================
__device__ __forceinline__ void cvt16_store(const float* __restrict__ src,
                                            unsigned short* dst) {
  const float4* p4 = (const float4*)src;
  float fv[16];
#pragma unroll
  for (int e = 0; e < 4; ++e) {
    float4 t = p4[e];
    fv[4 * e + 0] = t.x; fv[4 * e + 1] = t.y;
    fv[4 * e + 2] = t.z; fv[4 * e + 3] = t.w;
  }
  u16x8 lo, hi;
#pragma unroll
  for (int e = 0; e < 8; ++e) {
    lo[e] = __builtin_bit_cast(unsigned short, (__bf16)fv[e]);
    hi[e] = __builtin_bit_cast(unsigned short, (__bf16)fv[e + 8]);
  }
  *(u16x8*)dst = lo;
  *(u16x8*)(dst + 8) = hi;
}

#define LDS_STRIDE 40
__global__ __launch_bounds__(256, 2)
void hmu_main_f(const float* __restrict__ x, const float* __restrict__ mu,
                const float* __restrict__ lam, const float* __restrict__ v,
                const float* __restrict__ om, const float* __restrict__ ws,
                float* __restrict__ out) {
  __shared__ __align__(16) unsigned short As[BT * LDS_STRIDE];
  __shared__ __align__(16) unsigned short Bs[NT * 9 * LDS_STRIDE];
  const float* ws_x2 = ws;
  const float* ws_mu2 = ws + 1024;
  const float* ws_muv = ws + 9216;
  const int tid = threadIdx.x, lane = tid & 63, w = tid >> 6;
  const int m = lane & 15, kg = lane >> 4;
  const int n0 = blockIdx.x * NT, b0 = blockIdx.y * BT;
  f32x4 acc[2][9];
#pragma unroll
  for (int bs = 0; bs < 2; ++bs)
#pragma unroll
    for (int j = 0; j < 9; ++j) acc[bs][j] = (f32x4){0.f, 0.f, 0.f, 0.f};
  const int arow = tid >> 1, ahalf = tid & 1;
  for (int kt = 0; kt < 8; ++kt) {
    const int k0 = kt * 32;
    cvt16_store(x + (size_t)(b0 + arow) * D_SZ + k0 + ahalf * 16,
                &As[arow * LDS_STRIDE + ahalf * 16]);
#pragma unroll
    for (int it = 0; it < 2; ++it) {
      int idx = tid + 256 * it;
      if (idx < 288) {
        int row = idx >> 1, half = idx & 1;
        int nl = row / 9, j = row - nl * 9;
        const float* src = (j == 0)
            ? mu + (size_t)(n0 + nl) * D_SZ + k0 + half * 16
            : v + (size_t)((n0 + nl) * K_SZ + (j - 1)) * D_SZ + k0 + half * 16;
        cvt16_store(src, &Bs[row * LDS_STRIDE + half * 16]);
      }
    }
    __syncthreads();
    bf16x8 af[2];
#pragma unroll
    for (int bs = 0; bs < 2; ++bs)
      af[bs] = *(const bf16x8*)&As[((2 * w + bs) * 16 + m) * LDS_STRIDE + kg * 8];
#pragma unroll
    for (int j = 0; j < 9; ++j) {
      bf16x8 bfr = *(const bf16x8*)&Bs[(m * 9 + j) * LDS_STRIDE + kg * 8];
      acc[0][j] = __builtin_amdgcn_mfma_f32_16x16x32_bf16(af[0], bfr, acc[0][j], 0, 0, 0);
      acc[1][j] = __builtin_amdgcn_mfma_f32_16x16x32_bf16(af[1], bfr, acc[1][j], 0, 0, 0);
    }
    __syncthreads();
  }
  const int n = n0 + m;
  const float lam_n = lam[n];
  const float mu2_n = ws_mu2[n];
  float omr[8], muvr[8];
#pragma unroll
  for (int k = 0; k < 8; ++k) {
    omr[k] = om[n * 8 + k];
    muvr[k] = ws_muv[n * 8 + k];
  }
#pragma unroll
  for (int bs = 0; bs < 2; ++bs)
#pragma unroll
    for (int r = 0; r < 4; ++r) {
      int b = b0 + (2 * w + bs) * 16 + kg * 4 + r;
      float c0 = acc[bs][0][r];
      float q = lam_n * (ws_x2[b] - 2.f * c0 + mu2_n);
#pragma unroll
      for (int k = 0; k < 8; ++k) {
        float p = acc[bs][k + 1][r] - muvr[k];
        q = fmaf(omr[k] * p, p, q);
      }
      out[(size_t)b * N_SZ + n] = __expf(q * (-1.0f / 256.0f));
    }
}

__global__ void p2_mu_f(const float* __restrict__ mu, const float* __restrict__ v,
                        float* __restrict__ mu2, float* __restrict__ muv) {
  __shared__ __align__(16) float mulds[D_SZ];
  const int n = blockIdx.x;
  const int w = threadIdx.x >> 6, lane = threadIdx.x & 63;
  if (w == 0) {
    float4 m4 = *(const float4*)(mu + (size_t)n * D_SZ + 4 * lane);
    *(float4*)(mulds + 4 * lane) = m4;
    float s = m4.x * m4.x + m4.y * m4.y + m4.z * m4.z + m4.w * m4.w;
    s = wave_reduce(s);
    if (lane == 0) mu2[n] = s;
  }
  __syncthreads();
  float4 m4 = *(const float4*)(mulds + 4 * lane);
#pragma unroll
  for (int kk = 0; kk < 2; ++kk) {
    const int k = w * 2 + kk;
    float4 v4 = *(const float4*)(v + ((size_t)n * K_SZ + k) * D_SZ + 4 * lane);
    float s = m4.x * v4.x + m4.y * v4.y + m4.z * v4.z + m4.w * v4.w;
    s = wave_reduce(s);
    if (lane == 0) muv[n * K_SZ + k] = s;
  }
}

__global__ void p1_x2_f(const float* __restrict__ x, float* __restrict__ x2) {
  const int w = threadIdx.x >> 6, lane = threadIdx.x & 63;
  const int b = blockIdx.x * 4 + w;
  float4 t = *(const float4*)(x + (size_t)b * D_SZ + 4 * lane);
  float s = t.x * t.x + t.y * t.y + t.z * t.z + t.w * t.w;
  s = wave_reduce(s);
  if (lane == 0) x2[b] = s;
}

extern "C" void kernel_launch(void* const* d_in, const int* in_sizes, int n_in,
                              void* d_out, int out_size, void* d_ws, size_t ws_size,
                              hipStream_t stream) {
  const float* x   = (const float*)d_in[0];
  const float* mu  = (const float*)d_in[1];
  const float* lam = (const float*)d_in[2];
  const float* v   = (const float*)d_in[3];
  const float* om  = (const float*)d_in[4];
  float* out = (float*)d_out;
  char* wsb = (char*)d_ws;

  if (ws_size >= WS_NEED_P) {
    float* x2 = (float*)(wsb + WS_X2);
    unsigned short* px = (unsigned short*)(wsb + WS_PX);
    prep_x<<<B_SZ / 4, 256, 0, stream>>>(x, x2, px);
    hmu_pers<<<N_SZ / NT, 256, 0, stream>>>(px, mu, v, lam, om, x2, out);
  } else {
    float* wsf = (float*)d_ws;
    float* x2  = (float*)(wsb + WS_X2);
    float* mu2 = (float*)(wsb + WS_MU2F);
    float* muv = (float*)(wsb + WS_MUVF);
    dim3 grid(N_SZ / NT, B_SZ / BT);
    p1_x2_f<<<B_SZ / 4, 256, 0, stream>>>(x, x2);
    p2_mu_f<<<N_SZ, 256, 0, stream>>>(mu, v, mu2, muv);
    hmu_main_f<<<grid, 256, 0, stream>>>(x, mu, lam, v, om, wsf, out);
  }
}

// Round 2
// 209.599 us; speedup vs baseline: 1.2257x; 1.2257x over previous
//
#include <hip/hip_runtime.h>

// HMULayer omega: out[b][n] = exp(-(lam_n*||x_b-mu_n||^2 + sum_k om_nk*((x_b-mu_n).v_nk)^2)/D)
// B=1024, N=8192, D=256, K=8. 9 fused bf16 MFMA GEMMs sharing A=x.
// R6: back to R4 dataflow (prepacked pw) with two fixes driven by counters:
//  - prep_x+prep_w merged into ONE launch (prep_all): 1 wave per x-row / per n,
//    no block sync, no LDS. BW-floor ~114MB ≈ 18us.
//  - main kernel: XOR chunk-swizzle (phys = kg ^ ((row>>1)&3)) via pre-swizzled
//    glds16 SOURCE + swizzled ds_read (rule #21) kills the 8-way bank conflict
//    (5.77M conflict-cycles measured on R4's linear layout);
//    T3 minimum 2-phase: double-buffered LDS (34KB, 4 blocks/CU), STAGE(kt+1)
//    issued before compute(kt), ONE __syncthreads per K-step.

#define B_SZ 1024
#define N_SZ 8192
#define D_SZ 256
#define K_SZ 8

#define BT 128
#define NT 16

typedef __bf16 bf16x8 __attribute__((ext_vector_type(8)));
typedef float f32x4 __attribute__((ext_vector_type(4)));
typedef unsigned short u16x4 __attribute__((ext_vector_type(4)));
typedef unsigned short u16x8 __attribute__((ext_vector_type(8)));

// ws byte offsets (R4 layout)
#define WS_X2   0u          // f32[1024]
#define WS_MU2  4096u       // f32[8192]
#define WS_MUV  36864u      // f32[65536]
#define WS_PX   299008u     // bf16[1024*256]   (512 KB)
#define WS_PW   823296u     // bf16[8192*9*256] (36 MB)
#define WS_NEED (823296ull + 37748736ull)

__device__ __forceinline__ float wave_reduce(float s) {
#pragma unroll
  for (int off = 32; off > 0; off >>= 1) s += __shfl_down(s, off);
  return s;
}

__device__ __forceinline__ u16x4 cvt4(float4 t) {
  u16x4 r;
  r[0] = __builtin_bit_cast(unsigned short, (__bf16)t.x);
  r[1] = __builtin_bit_cast(unsigned short, (__bf16)t.y);
  r[2] = __builtin_bit_cast(unsigned short, (__bf16)t.z);
  r[3] = __builtin_bit_cast(unsigned short, (__bf16)t.w);
  return r;
}

__device__ __forceinline__ void glds16(const void* g, const void* l) {
  __builtin_amdgcn_global_load_lds(
      (const __attribute__((address_space(1))) void*)g,
      (__attribute__((address_space(3))) void*)l, 16, 0, 0);
}

// ---- prep_all: one wave per x-row (g<1024) or per n (g>=1024). ----
// x path: x2[b] + px bf16 pack.  w path: mu2[n], muv[n][k], pw rows.
__global__ void prep_all(const float* __restrict__ x, const float* __restrict__ mu,
                         const float* __restrict__ v,
                         float* __restrict__ x2, unsigned short* __restrict__ px,
                         float* __restrict__ mu2, float* __restrict__ muv,
                         unsigned short* __restrict__ pw) {
  const int w = threadIdx.x >> 6, lane = threadIdx.x & 63;
  const int g = blockIdx.x * 4 + w;
  if (g < B_SZ) {
    const int b = g;
    float4 t = *(const float4*)(x + (size_t)b * D_SZ + 4 * lane);
    *(u16x4*)(px + (size_t)b * D_SZ + 4 * lane) = cvt4(t);
    float s = t.x * t.x + t.y * t.y + t.z * t.z + t.w * t.w;
    s = wave_reduce(s);
    if (lane == 0) x2[b] = s;
  } else {
    const int n = g - B_SZ;
    float4 m4 = *(const float4*)(mu + (size_t)n * D_SZ + 4 * lane);
    *(u16x4*)(pw + (size_t)n * 9 * D_SZ + 4 * lane) = cvt4(m4);
    float s2 = m4.x * m4.x + m4.y * m4.y + m4.z * m4.z + m4.w * m4.w;
    float dk[K_SZ];
#pragma unroll
    for (int k = 0; k < K_SZ; ++k) {
      float4 v4 = *(const float4*)(v + ((size_t)n * K_SZ + k) * D_SZ + 4 * lane);
      *(u16x4*)(pw + ((size_t)n * 9 + k + 1) * D_SZ + 4 * lane) = cvt4(v4);
      dk[k] = m4.x * v4.x + m4.y * v4.y + m4.z * v4.z + m4.w * v4.w;
    }
    s2 = wave_reduce(s2);
    if (lane == 0) mu2[n] = s2;
#pragma unroll
    for (int k = 0; k < K_SZ; ++k) {
      float r = wave_reduce(dk[k]);
      if (lane == 0) muv[n * K_SZ + k] = r;
    }
  }
}

// stage one K-step tile into one LDS buffer.
// LDS dest is linear (glds16 requirement); global SOURCE chunk is
// pre-swizzled: physical chunk ch holds logical chunk ch ^ ((row>>1)&3).
__device__ __forceinline__ void stage_tile(const unsigned short* __restrict__ px,
                                           const unsigned short* __restrict__ pw,
                                           unsigned short* As, unsigned short* Bs,
                                           int b0, int n0, int k0, int w, int lane) {
  const int nl4 = lane >> 2;           // row within 16
  const int ch = lane & 3;             // physical 16B chunk within 64B row
  const int kc = (ch ^ ((nl4 >> 1) & 3)) * 8;  // logical chunk -> elem offset
#pragma unroll
  for (int t = 0; t < 2; ++t) {
    int r0 = w * 32 + t * 16;
    glds16(px + (size_t)(b0 + r0 + nl4) * D_SZ + k0 + kc, As + r0 * 32);
  }
#pragma unroll
  for (int t = 0; t < 3; ++t) {
    int i = w + 4 * t;                 // wave-uniform guard
    if (i < 9)
      glds16(pw + ((size_t)(n0 + nl4) * 9 + i) * D_SZ + k0 + kc, Bs + i * 16 * 32);
  }
}

// ---- main (prepacked): 2-phase double-buffered, swizzled LDS reads ----
__global__ __launch_bounds__(256, 4)
void hmu_main_p(const unsigned short* __restrict__ px,
                const unsigned short* __restrict__ pw,
                const float* __restrict__ lam, const float* __restrict__ om,
                const float* __restrict__ wsf, float* __restrict__ out) {
  __shared__ __align__(16) unsigned short As[2][BT * 32];       // 2 x 8 KB
  __shared__ __align__(16) unsigned short Bs[2][NT * 9 * 32];   // 2 x 9 KB

  const float* ws_x2 = wsf;                    // WS_X2/4
  const float* ws_mu2 = wsf + 1024;            // WS_MU2/4
  const float* ws_muv = wsf + 9216;            // WS_MUV/4

  const int tid = threadIdx.x;
  const int lane = tid & 63;
  const int w = tid >> 6;
  const int m = lane & 15;
  const int kg = lane >> 4;

  const int n0 = blockIdx.x * NT;
  const int b0 = blockIdx.y * BT;

  f32x4 acc[2][9];
#pragma unroll
  for (int bs = 0; bs < 2; ++bs)
#pragma unroll
    for (int j = 0; j < 9; ++j) acc[bs][j] = (f32x4){0.f, 0.f, 0.f, 0.f};

  // read-side swizzled chunk offset (elems): logical kg lives at phys kg^((row>>1)&3)
  const int sw = (kg ^ ((m >> 1) & 3)) * 8;

  // prologue: stage kt=0 into buffer 0
  stage_tile(px, pw, As[0], Bs[0], b0, n0, 0, w, lane);
  __syncthreads();

  for (int kt = 0; kt < 8; ++kt) {
    const int cur = kt & 1;
    if (kt < 7)
      stage_tile(px, pw, As[cur ^ 1], Bs[cur ^ 1], b0, n0, (kt + 1) * 32, w, lane);

    const unsigned short* Ac = As[cur];
    const unsigned short* Bc = Bs[cur];
    bf16x8 af0 = *(const bf16x8*)&Ac[((2 * w + 0) * 16 + m) * 32 + sw];
    bf16x8 af1 = *(const bf16x8*)&Ac[((2 * w + 1) * 16 + m) * 32 + sw];
#pragma unroll
    for (int j = 0; j < 9; ++j) {
      bf16x8 bfr = *(const bf16x8*)&Bc[(j * 16 + m) * 32 + sw];
      acc[0][j] = __builtin_amdgcn_mfma_f32_16x16x32_bf16(af0, bfr, acc[0][j], 0, 0, 0);
      acc[1][j] = __builtin_amdgcn_mfma_f32_16x16x32_bf16(af1, bfr, acc[1][j], 0, 0, 0);
    }
    if (kt < 7) __syncthreads();  // drains vmcnt(0)+lgkmcnt(0): next buf ready,
                                  // this buf's reads complete before overwrite
  }

  // epilogue: C/D layout col(n)=lane&15, row(b)=kg*4+reg
  const int n = n0 + m;
  const float lam_n = lam[n];
  const float mu2_n = ws_mu2[n];
  float omr[8], muvr[8];
#pragma unroll
  for (int k = 0; k < 8; ++k) {
    omr[k] = om[n * 8 + k];
    muvr[k] = ws_muv[n * 8 + k];
  }
#pragma unroll
  for (int bs = 0; bs < 2; ++bs) {
#pragma unroll
    for (int r = 0; r < 4; ++r) {
      int b = b0 + (2 * w + bs) * 16 + kg * 4 + r;
      float x2b = ws_x2[b];
      float c0 = acc[bs][0][r];
      float q = lam_n * (x2b - 2.f * c0 + mu2_n);
#pragma unroll
      for (int k = 0; k < 8; ++k) {
        float p = acc[bs][k + 1][r] - muvr[k];
        q = fmaf(omr[k] * p, p, q);
      }
      out[(size_t)b * N_SZ + n] = __expf(q * (-1.0f / 256.0f));
    }
  }
}

// ================= fallback path (R2): in-loop cvt staging =================
__device__ __forceinline__ void cvt16_store(const float* __restrict__ src,
                                            unsigned short* dst) {
  const float4* p4 = (const float4*)src;
  float fv[16];
#pragma unroll
  for (int e = 0; e < 4; ++e) {
    float4 t = p4[e];
    fv[4 * e + 0] = t.x; fv[4 * e + 1] = t.y;
    fv[4 * e + 2] = t.z; fv[4 * e + 3] = t.w;
  }
  u16x8 lo, hi;
#pragma unroll
  for (int e = 0; e < 8; ++e) {
    lo[e] = __builtin_bit_cast(unsigned short, (__bf16)fv[e]);
    hi[e] = __builtin_bit_cast(unsigned short, (__bf16)fv[e + 8]);
  }
  *(u16x8*)dst = lo;
  *(u16x8*)(dst + 8) = hi;
}

#define LDS_STRIDE 40
__global__ __launch_bounds__(256, 2)
void hmu_main_f(const float* __restrict__ x, const float* __restrict__ mu,
                const float* __restrict__ lam, const float* __restrict__ v,
                const float* __restrict__ om, const float* __restrict__ ws,
                float* __restrict__ out) {
  __shared__ __align__(16) unsigned short As[BT * LDS_STRIDE];
  __shared__ __align__(16) unsigned short Bs[NT * 9 * LDS_STRIDE];
  const float* ws_x2 = ws;
  const float* ws_mu2 = ws + 1024;
  const float* ws_muv = ws + 9216;
  const int tid = threadIdx.x, lane = tid & 63, w = tid >> 6;
  const int m = lane & 15, kg = lane >> 4;
  const int n0 = blockIdx.x * NT, b0 = blockIdx.y * BT;
  f32x4 acc[2][9];
#pragma unroll
  for (int bs = 0; bs < 2; ++bs)
#pragma unroll
    for (int j = 0; j < 9; ++j) acc[bs][j] = (f32x4){0.f, 0.f, 0.f, 0.f};
  const int arow = tid >> 1, ahalf = tid & 1;
  for (int kt = 0; kt < 8; ++kt) {
    const int k0 = kt * 32;
    cvt16_store(x + (size_t)(b0 + arow) * D_SZ + k0 + ahalf * 16,
                &As[arow * LDS_STRIDE + ahalf * 16]);
#pragma unroll
    for (int it = 0; it < 2; ++it) {
      int idx = tid + 256 * it;
      if (idx < 288) {
        int row = idx >> 1, half = idx & 1;
        int nl = row / 9, j = row - nl * 9;
        const float* src = (j == 0)
            ? mu + (size_t)(n0 + nl) * D_SZ + k0 + half * 16
            : v + (size_t)((n0 + nl) * K_SZ + (j - 1)) * D_SZ + k0 + half * 16;
        cvt16_store(src, &Bs[row * LDS_STRIDE + half * 16]);
      }
    }
    __syncthreads();
    bf16x8 af[2];
#pragma unroll
    for (int bs = 0; bs < 2; ++bs)
      af[bs] = *(const bf16x8*)&As[((2 * w + bs) * 16 + m) * LDS_STRIDE + kg * 8];
#pragma unroll
    for (int j = 0; j < 9; ++j) {
      bf16x8 bfr = *(const bf16x8*)&Bs[(m * 9 + j) * LDS_STRIDE + kg * 8];
      acc[0][j] = __builtin_amdgcn_mfma_f32_16x16x32_bf16(af[0], bfr, acc[0][j], 0, 0, 0);
      acc[1][j] = __builtin_amdgcn_mfma_f32_16x16x32_bf16(af[1], bfr, acc[1][j], 0, 0, 0);
    }
    __syncthreads();
  }
  const int n = n0 + m;
  const float lam_n = lam[n];
  const float mu2_n = ws_mu2[n];
  float omr[8], muvr[8];
#pragma unroll
  for (int k = 0; k < 8; ++k) {
    omr[k] = om[n * 8 + k];
    muvr[k] = ws_muv[n * 8 + k];
  }
#pragma unroll
  for (int bs = 0; bs < 2; ++bs)
#pragma unroll
    for (int r = 0; r < 4; ++r) {
      int b = b0 + (2 * w + bs) * 16 + kg * 4 + r;
      float c0 = acc[bs][0][r];
      float q = lam_n * (ws_x2[b] - 2.f * c0 + mu2_n);
#pragma unroll
      for (int k = 0; k < 8; ++k) {
        float p = acc[bs][k + 1][r] - muvr[k];
        q = fmaf(omr[k] * p, p, q);
      }
      out[(size_t)b * N_SZ + n] = __expf(q * (-1.0f / 256.0f));
    }
}

__global__ void p2_mu_f(const float* __restrict__ mu, const float* __restrict__ v,
                        float* __restrict__ mu2, float* __restrict__ muv) {
  __shared__ __align__(16) float mulds[D_SZ];
  const int n = blockIdx.x;
  const int w = threadIdx.x >> 6, lane = threadIdx.x & 63;
  if (w == 0) {
    float4 m4 = *(const float4*)(mu + (size_t)n * D_SZ + 4 * lane);
    *(float4*)(mulds + 4 * lane) = m4;
    float s = m4.x * m4.x + m4.y * m4.y + m4.z * m4.z + m4.w * m4.w;
    s = wave_reduce(s);
    if (lane == 0) mu2[n] = s;
  }
  __syncthreads();
  float4 m4 = *(const float4*)(mulds + 4 * lane);
#pragma unroll
  for (int kk = 0; kk < 2; ++kk) {
    const int k = w * 2 + kk;
    float4 v4 = *(const float4*)(v + ((size_t)n * K_SZ + k) * D_SZ + 4 * lane);
    float s = m4.x * v4.x + m4.y * v4.y + m4.z * v4.z + m4.w * v4.w;
    s = wave_reduce(s);
    if (lane == 0) muv[n * K_SZ + k] = s;
  }
}

__global__ void p1_x2_f(const float* __restrict__ x, float* __restrict__ x2) {
  const int w = threadIdx.x >> 6, lane = threadIdx.x & 63;
  const int b = blockIdx.x * 4 + w;
  float4 t = *(const float4*)(x + (size_t)b * D_SZ + 4 * lane);
  float s = t.x * t.x + t.y * t.y + t.z * t.z + t.w * t.w;
  s = wave_reduce(s);
  if (lane == 0) x2[b] = s;
}

extern "C" void kernel_launch(void* const* d_in, const int* in_sizes, int n_in,
                              void* d_out, int out_size, void* d_ws, size_t ws_size,
                              hipStream_t stream) {
  const float* x   = (const float*)d_in[0];
  const float* mu  = (const float*)d_in[1];
  const float* lam = (const float*)d_in[2];
  const float* v   = (const float*)d_in[3];
  const float* om  = (const float*)d_in[4];
  float* out = (float*)d_out;
  char* wsb = (char*)d_ws;
  float* wsf = (float*)d_ws;
  float* x2  = (float*)(wsb + WS_X2);
  float* mu2 = (float*)(wsb + WS_MU2);
  float* muv = (float*)(wsb + WS_MUV);

  dim3 grid(N_SZ / NT, B_SZ / BT);
  if (ws_size >= WS_NEED) {
    unsigned short* px = (unsigned short*)(wsb + WS_PX);
    unsigned short* pw = (unsigned short*)(wsb + WS_PW);
    prep_all<<<(B_SZ + N_SZ) / 4, 256, 0, stream>>>(x, mu, v, x2, px, mu2, muv, pw);
    hmu_main_p<<<grid, 256, 0, stream>>>(px, pw, lam, om, wsf, out);
  } else {
    p1_x2_f<<<B_SZ / 4, 256, 0, stream>>>(x, x2);
    p2_mu_f<<<N_SZ, 256, 0, stream>>>(mu, v, mu2, muv);
    hmu_main_f<<<grid, 256, 0, stream>>>(x, mu, lam, v, om, wsf, out);
  }
}

// Round 3
// 172.554 us; speedup vs baseline: 1.4889x; 1.2147x over previous
//
#include <hip/hip_runtime.h>

// HMULayer omega: out[b][n] = exp(-(lam_n*||x_b-mu_n||^2 + sum_k om_nk*((x_b-mu_n).v_nk)^2)/D)
// B=1024, N=8192, D=256, K=8. 9 fused bf16 MFMA GEMMs sharing A=x.
// R7: isolate variables after R6 regression (2-phase + 4blk/CU thrashed L2:
//     FETCH 80->117MB, WRITE 32->127MB; swizzle itself was clean: conflicts->0).
//  - main: R4-EXACT structure (single 17KB buffer, 2 barriers/K-step, (256,2))
//    + ONLY the XOR chunk swizzle (phys = kg ^ ((row>>1)&3)) via pre-swizzled
//    glds16 SOURCE + swizzled ds_read. One variable vs R4.
//  - prep_all v2: one wave per UNIT-ROW (x-row / mu-row / v-row) = 74752 waves,
//    single 6-shfl reduce per wave (was 9 dependent chains/wave). mu re-reads
//    are L2-hits (the 8 v-waves of an n are adjacent blocks).

#define B_SZ 1024
#define N_SZ 8192
#define D_SZ 256
#define K_SZ 8

#define BT 128
#define NT 16

typedef __bf16 bf16x8 __attribute__((ext_vector_type(8)));
typedef float f32x4 __attribute__((ext_vector_type(4)));
typedef unsigned short u16x4 __attribute__((ext_vector_type(4)));
typedef unsigned short u16x8 __attribute__((ext_vector_type(8)));

// ws byte offsets (R4 layout)
#define WS_X2   0u          // f32[1024]
#define WS_MU2  4096u       // f32[8192]
#define WS_MUV  36864u      // f32[65536]
#define WS_PX   299008u     // bf16[1024*256]   (512 KB)
#define WS_PW   823296u     // bf16[8192*9*256] (36 MB)
#define WS_NEED (823296ull + 37748736ull)

__device__ __forceinline__ float wave_reduce(float s) {
#pragma unroll
  for (int off = 32; off > 0; off >>= 1) s += __shfl_down(s, off);
  return s;
}

__device__ __forceinline__ u16x4 cvt4(float4 t) {
  u16x4 r;
  r[0] = __builtin_bit_cast(unsigned short, (__bf16)t.x);
  r[1] = __builtin_bit_cast(unsigned short, (__bf16)t.y);
  r[2] = __builtin_bit_cast(unsigned short, (__bf16)t.z);
  r[3] = __builtin_bit_cast(unsigned short, (__bf16)t.w);
  return r;
}

__device__ __forceinline__ void glds16(const void* g, const void* l) {
  __builtin_amdgcn_global_load_lds(
      (const __attribute__((address_space(1))) void*)g,
      (__attribute__((address_space(3))) void*)l, 16, 0, 0);
}

// ---- prep_all v2: one wave per row. g<1024: x-row. g<9216: mu-row. else v-row.
__global__ void prep_all(const float* __restrict__ x, const float* __restrict__ mu,
                         const float* __restrict__ v,
                         float* __restrict__ x2, unsigned short* __restrict__ px,
                         float* __restrict__ mu2, float* __restrict__ muv,
                         unsigned short* __restrict__ pw) {
  const int w = threadIdx.x >> 6, lane = threadIdx.x & 63;
  const int g = blockIdx.x * 4 + w;
  if (g < B_SZ) {
    const int b = g;
    float4 t = *(const float4*)(x + (size_t)b * D_SZ + 4 * lane);
    *(u16x4*)(px + (size_t)b * D_SZ + 4 * lane) = cvt4(t);
    float s = t.x * t.x + t.y * t.y + t.z * t.z + t.w * t.w;
    s = wave_reduce(s);
    if (lane == 0) x2[b] = s;
  } else if (g < B_SZ + N_SZ) {
    const int n = g - B_SZ;
    float4 m4 = *(const float4*)(mu + (size_t)n * D_SZ + 4 * lane);
    *(u16x4*)(pw + (size_t)n * 9 * D_SZ + 4 * lane) = cvt4(m4);
    float s = m4.x * m4.x + m4.y * m4.y + m4.z * m4.z + m4.w * m4.w;
    s = wave_reduce(s);
    if (lane == 0) mu2[n] = s;
  } else {
    const int idx = g - (B_SZ + N_SZ);
    const int n = idx >> 3, k = idx & 7;
    float4 m4 = *(const float4*)(mu + (size_t)n * D_SZ + 4 * lane);
    float4 v4 = *(const float4*)(v + ((size_t)n * K_SZ + k) * D_SZ + 4 * lane);
    *(u16x4*)(pw + ((size_t)n * 9 + k + 1) * D_SZ + 4 * lane) = cvt4(v4);
    float s = m4.x * v4.x + m4.y * v4.y + m4.z * v4.z + m4.w * v4.w;
    s = wave_reduce(s);
    if (lane == 0) muv[n * K_SZ + k] = s;
  }
}

// stage one K-step tile (linear LDS dest; global SOURCE chunk pre-swizzled:
// physical chunk ch holds logical chunk ch ^ ((row>>1)&3))
__device__ __forceinline__ void stage_tile(const unsigned short* __restrict__ px,
                                           const unsigned short* __restrict__ pw,
                                           unsigned short* As, unsigned short* Bs,
                                           int b0, int n0, int k0, int w, int lane) {
  const int nl4 = lane >> 2;           // row within 16
  const int ch = lane & 3;             // physical 16B chunk within 64B row
  const int kc = (ch ^ ((nl4 >> 1) & 3)) * 8;  // logical elem offset
#pragma unroll
  for (int t = 0; t < 2; ++t) {
    int r0 = w * 32 + t * 16;
    glds16(px + (size_t)(b0 + r0 + nl4) * D_SZ + k0 + kc, As + r0 * 32);
  }
#pragma unroll
  for (int t = 0; t < 3; ++t) {
    int i = w + 4 * t;                 // wave-uniform guard
    if (i < 9)
      glds16(pw + ((size_t)(n0 + nl4) * 9 + i) * D_SZ + k0 + kc, Bs + i * 16 * 32);
  }
}

// ---- main: R4 structure (single buffer, 2 barriers/K-step) + swizzle ----
__global__ __launch_bounds__(256, 2)
void hmu_main_p(const unsigned short* __restrict__ px,
                const unsigned short* __restrict__ pw,
                const float* __restrict__ lam, const float* __restrict__ om,
                const float* __restrict__ wsf, float* __restrict__ out) {
  __shared__ __align__(16) unsigned short As[BT * 32];       // 8 KB
  __shared__ __align__(16) unsigned short Bs[NT * 9 * 32];   // 9 KB

  const float* ws_x2 = wsf;                    // WS_X2/4
  const float* ws_mu2 = wsf + 1024;            // WS_MU2/4
  const float* ws_muv = wsf + 9216;            // WS_MUV/4

  const int tid = threadIdx.x;
  const int lane = tid & 63;
  const int w = tid >> 6;
  const int m = lane & 15;
  const int kg = lane >> 4;

  const int n0 = blockIdx.x * NT;
  const int b0 = blockIdx.y * BT;

  f32x4 acc[2][9];
#pragma unroll
  for (int bs = 0; bs < 2; ++bs)
#pragma unroll
    for (int j = 0; j < 9; ++j) acc[bs][j] = (f32x4){0.f, 0.f, 0.f, 0.f};

  // read-side swizzle: logical chunk kg of row m lives at phys kg^((m>>1)&3)
  const int sw = (kg ^ ((m >> 1) & 3)) * 8;

  for (int kt = 0; kt < 8; ++kt) {
    stage_tile(px, pw, As, Bs, b0, n0, kt * 32, w, lane);
    __syncthreads();   // compiler emits s_waitcnt vmcnt(0) before barrier

    bf16x8 af0 = *(const bf16x8*)&As[((2 * w + 0) * 16 + m) * 32 + sw];
    bf16x8 af1 = *(const bf16x8*)&As[((2 * w + 1) * 16 + m) * 32 + sw];
#pragma unroll
    for (int j = 0; j < 9; ++j) {
      bf16x8 bfr = *(const bf16x8*)&Bs[(j * 16 + m) * 32 + sw];
      acc[0][j] = __builtin_amdgcn_mfma_f32_16x16x32_bf16(af0, bfr, acc[0][j], 0, 0, 0);
      acc[1][j] = __builtin_amdgcn_mfma_f32_16x16x32_bf16(af1, bfr, acc[1][j], 0, 0, 0);
    }
    __syncthreads();
  }

  // epilogue: C/D layout col(n)=lane&15, row(b)=kg*4+reg
  const int n = n0 + m;
  const float lam_n = lam[n];
  const float mu2_n = ws_mu2[n];
  float omr[8], muvr[8];
#pragma unroll
  for (int k = 0; k < 8; ++k) {
    omr[k] = om[n * 8 + k];
    muvr[k] = ws_muv[n * 8 + k];
  }
#pragma unroll
  for (int bs = 0; bs < 2; ++bs) {
#pragma unroll
    for (int r = 0; r < 4; ++r) {
      int b = b0 + (2 * w + bs) * 16 + kg * 4 + r;
      float x2b = ws_x2[b];
      float c0 = acc[bs][0][r];
      float q = lam_n * (x2b - 2.f * c0 + mu2_n);
#pragma unroll
      for (int k = 0; k < 8; ++k) {
        float p = acc[bs][k + 1][r] - muvr[k];
        q = fmaf(omr[k] * p, p, q);
      }
      out[(size_t)b * N_SZ + n] = __expf(q * (-1.0f / 256.0f));
    }
  }
}

// ================= fallback path (R2): in-loop cvt staging =================
__device__ __forceinline__ void cvt16_store(const float* __restrict__ src,
                                            unsigned short* dst) {
  const float4* p4 = (const float4*)src;
  float fv[16];
#pragma unroll
  for (int e = 0; e < 4; ++e) {
    float4 t = p4[e];
    fv[4 * e + 0] = t.x; fv[4 * e + 1] = t.y;
    fv[4 * e + 2] = t.z; fv[4 * e + 3] = t.w;
  }
  u16x8 lo, hi;
#pragma unroll
  for (int e = 0; e < 8; ++e) {
    lo[e] = __builtin_bit_cast(unsigned short, (__bf16)fv[e]);
    hi[e] = __builtin_bit_cast(unsigned short, (__bf16)fv[e + 8]);
  }
  *(u16x8*)dst = lo;
  *(u16x8*)(dst + 8) = hi;
}

#define LDS_STRIDE 40
__global__ __launch_bounds__(256, 2)
void hmu_main_f(const float* __restrict__ x, const float* __restrict__ mu,
                const float* __restrict__ lam, const float* __restrict__ v,
                const float* __restrict__ om, const float* __restrict__ ws,
                float* __restrict__ out) {
  __shared__ __align__(16) unsigned short As[BT * LDS_STRIDE];
  __shared__ __align__(16) unsigned short Bs[NT * 9 * LDS_STRIDE];
  const float* ws_x2 = ws;
  const float* ws_mu2 = ws + 1024;
  const float* ws_muv = ws + 9216;
  const int tid = threadIdx.x, lane = tid & 63, w = tid >> 6;
  const int m = lane & 15, kg = lane >> 4;
  const int n0 = blockIdx.x * NT, b0 = blockIdx.y * BT;
  f32x4 acc[2][9];
#pragma unroll
  for (int bs = 0; bs < 2; ++bs)
#pragma unroll
    for (int j = 0; j < 9; ++j) acc[bs][j] = (f32x4){0.f, 0.f, 0.f, 0.f};
  const int arow = tid >> 1, ahalf = tid & 1;
  for (int kt = 0; kt < 8; ++kt) {
    const int k0 = kt * 32;
    cvt16_store(x + (size_t)(b0 + arow) * D_SZ + k0 + ahalf * 16,
                &As[arow * LDS_STRIDE + ahalf * 16]);
#pragma unroll
    for (int it = 0; it < 2; ++it) {
      int idx = tid + 256 * it;
      if (idx < 288) {
        int row = idx >> 1, half = idx & 1;
        int nl = row / 9, j = row - nl * 9;
        const float* src = (j == 0)
            ? mu + (size_t)(n0 + nl) * D_SZ + k0 + half * 16
            : v + (size_t)((n0 + nl) * K_SZ + (j - 1)) * D_SZ + k0 + half * 16;
        cvt16_store(src, &Bs[row * LDS_STRIDE + half * 16]);
      }
    }
    __syncthreads();
    bf16x8 af[2];
#pragma unroll
    for (int bs = 0; bs < 2; ++bs)
      af[bs] = *(const bf16x8*)&As[((2 * w + bs) * 16 + m) * LDS_STRIDE + kg * 8];
#pragma unroll
    for (int j = 0; j < 9; ++j) {
      bf16x8 bfr = *(const bf16x8*)&Bs[(m * 9 + j) * LDS_STRIDE + kg * 8];
      acc[0][j] = __builtin_amdgcn_mfma_f32_16x16x32_bf16(af[0], bfr, acc[0][j], 0, 0, 0);
      acc[1][j] = __builtin_amdgcn_mfma_f32_16x16x32_bf16(af[1], bfr, acc[1][j], 0, 0, 0);
    }
    __syncthreads();
  }
  const int n = n0 + m;
  const float lam_n = lam[n];
  const float mu2_n = ws_mu2[n];
  float omr[8], muvr[8];
#pragma unroll
  for (int k = 0; k < 8; ++k) {
    omr[k] = om[n * 8 + k];
    muvr[k] = ws_muv[n * 8 + k];
  }
#pragma unroll
  for (int bs = 0; bs < 2; ++bs)
#pragma unroll
    for (int r = 0; r < 4; ++r) {
      int b = b0 + (2 * w + bs) * 16 + kg * 4 + r;
      float c0 = acc[bs][0][r];
      float q = lam_n * (ws_x2[b] - 2.f * c0 + mu2_n);
#pragma unroll
      for (int k = 0; k < 8; ++k) {
        float p = acc[bs][k + 1][r] - muvr[k];
        q = fmaf(omr[k] * p, p, q);
      }
      out[(size_t)b * N_SZ + n] = __expf(q * (-1.0f / 256.0f));
    }
}

__global__ void p2_mu_f(const float* __restrict__ mu, const float* __restrict__ v,
                        float* __restrict__ mu2, float* __restrict__ muv) {
  __shared__ __align__(16) float mulds[D_SZ];
  const int n = blockIdx.x;
  const int w = threadIdx.x >> 6, lane = threadIdx.x & 63;
  if (w == 0) {
    float4 m4 = *(const float4*)(mu + (size_t)n * D_SZ + 4 * lane);
    *(float4*)(mulds + 4 * lane) = m4;
    float s = m4.x * m4.x + m4.y * m4.y + m4.z * m4.z + m4.w * m4.w;
    s = wave_reduce(s);
    if (lane == 0) mu2[n] = s;
  }
  __syncthreads();
  float4 m4 = *(const float4*)(mulds + 4 * lane);
#pragma unroll
  for (int kk = 0; kk < 2; ++kk) {
    const int k = w * 2 + kk;
    float4 v4 = *(const float4*)(v + ((size_t)n * K_SZ + k) * D_SZ + 4 * lane);
    float s = m4.x * v4.x + m4.y * v4.y + m4.z * v4.z + m4.w * v4.w;
    s = wave_reduce(s);
    if (lane == 0) muv[n * K_SZ + k] = s;
  }
}

__global__ void p1_x2_f(const float* __restrict__ x, float* __restrict__ x2) {
  const int w = threadIdx.x >> 6, lane = threadIdx.x & 63;
  const int b = blockIdx.x * 4 + w;
  float4 t = *(const float4*)(x + (size_t)b * D_SZ + 4 * lane);
  float s = t.x * t.x + t.y * t.y + t.z * t.z + t.w * t.w;
  s = wave_reduce(s);
  if (lane == 0) x2[b] = s;
}

extern "C" void kernel_launch(void* const* d_in, const int* in_sizes, int n_in,
                              void* d_out, int out_size, void* d_ws, size_t ws_size,
                              hipStream_t stream) {
  const float* x   = (const float*)d_in[0];
  const float* mu  = (const float*)d_in[1];
  const float* lam = (const float*)d_in[2];
  const float* v   = (const float*)d_in[3];
  const float* om  = (const float*)d_in[4];
  float* out = (float*)d_out;
  char* wsb = (char*)d_ws;
  float* wsf = (float*)d_ws;
  float* x2  = (float*)(wsb + WS_X2);
  float* mu2 = (float*)(wsb + WS_MU2);
  float* muv = (float*)(wsb + WS_MUV);

  dim3 grid(N_SZ / NT, B_SZ / BT);
  if (ws_size >= WS_NEED) {
    unsigned short* px = (unsigned short*)(wsb + WS_PX);
    unsigned short* pw = (unsigned short*)(wsb + WS_PW);
    const int nunits = B_SZ + N_SZ + N_SZ * K_SZ;   // 74752 waves
    prep_all<<<nunits / 4, 256, 0, stream>>>(x, mu, v, x2, px, mu2, muv, pw);
    hmu_main_p<<<grid, 256, 0, stream>>>(px, pw, lam, om, wsf, out);
  } else {
    p1_x2_f<<<B_SZ / 4, 256, 0, stream>>>(x, x2);
    p2_mu_f<<<N_SZ, 256, 0, stream>>>(mu, v, mu2, muv);
    hmu_main_f<<<grid, 256, 0, stream>>>(x, mu, lam, v, om, wsf, out);
  }
}